// Round 1
// baseline (33.307 us; speedup 1.0000x reference)
//
#include <hip/hip_runtime.h>

// GraphLookup: atoms [B,A,F] f32, edges [B,A,D] int32 (neighbor idx, -1 = none)
// out [B,A,D+1,F]: out[:,:,0,:] = atoms; out[:,:,1+d,:] = atoms[b, edges[b,a,d], :]
//
// Round-N structure: DIRECT GATHER, no atoms staging.
// Each batch's atoms slab is only 15.9 KB -> it L1/L2-fits trivially, so the
// previous LDS double-buffer + global_load_lds pipeline was pure overhead
// (staging data that cache-fits, plus whole-GPU lockstep barrier drains).
// Now: 1024 blocks x 512 threads (4 blocks/CU), one batch per block,
// only a 2.25 KB LDS row table + ONE barrier; the gather reads hit L1/L2
// and the store stream flows continuously with no vmcnt(0) breathing.

typedef float f32x4 __attribute__((ext_vector_type(4)));

constexpr unsigned B  = 1024;
constexpr unsigned A  = 64;
constexpr unsigned D  = 8;
constexpr unsigned F  = 62;
constexpr unsigned K  = D + 1;                   // 9 output rows per atom
constexpr unsigned F2 = F / 2;                   // 31 float2 per feature row
constexpr unsigned ROWTAB = A * K;               // 576 source-row entries
constexpr unsigned OUT4_PER_B = A * K * F / 4;   // 8928 float4 per batch
constexpr unsigned NT = 512;                     // threads per block

__global__ __launch_bounds__(NT, 8)              // 8 waves/EU -> 4 blocks/CU
void graph_lookup_kernel(const float2* __restrict__ atoms2,
                         const int*   __restrict__ edges,
                         f32x4*       __restrict__ out4)
{
    __shared__ int s_row[ROWTAB];                // 2.25 KB

    const unsigned tid = threadIdx.x;
    const unsigned b   = blockIdx.x;

    const float2* __restrict__ at = atoms2 + (size_t)b * (A * F2);

    // Row table: row r = a*K + k maps to source atom index (self or neighbor).
    {
        const int e = edges[(size_t)b * (A * D) + tid];   // A*D == NT == 512
        if (tid < A) s_row[tid * K] = (int)tid;           // k == 0: self
        s_row[(tid >> 3) * K + (tid & 7) + 1] = e;        // k = 1..8: edges
    }
    __syncthreads();                                      // only barrier

    f32x4* __restrict__ dst = out4 + (size_t)b * OUT4_PER_B;

    // Flat f32x4 store stream; each f32x4 covers two float2 source elements
    // that may straddle a row boundary (rows are 31 float2).
    for (unsigned t = tid; t < OUT4_PER_B; t += NT) {
        const unsigned o  = 2 * t;                 // float2 index
        const unsigned r0 = o / F2;                // magic-mul div by 31
        const unsigned e0 = o - r0 * F2;
        const bool cross  = (e0 == F2 - 1);        // second half rolls to next row
        const unsigned r1 = r0 + (cross ? 1u : 0u);
        const unsigned e1 = cross ? 0u : e0 + 1u;

        const int idx0 = s_row[r0];
        const int idx1 = s_row[r1];

        const float2 h0 = (idx0 >= 0) ? at[(unsigned)idx0 * F2 + e0]
                                      : make_float2(0.0f, 0.0f);
        const float2 h1 = (idx1 >= 0) ? at[(unsigned)idx1 * F2 + e1]
                                      : make_float2(0.0f, 0.0f);

        f32x4 v = { h0.x, h0.y, h1.x, h1.y };
        dst[t] = v;
    }
}

extern "C" void kernel_launch(void* const* d_in, const int* in_sizes, int n_in,
                              void* d_out, int out_size, void* d_ws, size_t ws_size,
                              hipStream_t stream) {
    const float2* atoms2 = (const float2*)d_in[0];
    const int*    edges  = (const int*)d_in[1];
    f32x4*        out4   = (f32x4*)d_out;

    graph_lookup_kernel<<<B, NT, 0, stream>>>(atoms2, edges, out4);
}

// Round 2
// 29.882 us; speedup vs baseline: 1.1146x; 1.1146x over previous
//
#include <hip/hip_runtime.h>

// GraphLookup: atoms [B,A,F] f32, edges [B,A,D] int32 (neighbor idx, -1 = none)
// out [B,A,D+1,F]: out[:,:,0,:] = atoms; out[:,:,1+d,:] = atoms[b, edges[b,a,d], :]
//
// Structure (proven best): 512 blocks x 512 threads, 2 batches/block,
// double-buffered LDS slabs staged with async global_load_lds.
// Round-2 change: COUNTED-vmcnt barriers (T4). __syncthreads() emitted
// s_waitcnt vmcnt(0), draining the whole GPU's in-flight store queue at
// two lockstep points per block. Replaced with
//   asm("s_waitcnt vmcnt(N) lgkmcnt(0)") + raw s_barrier
// so up to 17 output stores stay in flight across the mid barrier, and
// b1's stage DMA overlaps b0's stage latency AND b0's store stream.
//
// Per-wave VMEM issue order (enforced by sched_barrier(0)):
//   [b0-DMA x2, e0, e1] | [b1-DMA x2] | 17-18 stores | wait vmcnt(17)
// vmcnt(2) at prologue: retires b0 DMA + e-loads, leaves b1 DMA in flight.
// vmcnt(17) at mid: every wave has 2 DMA + 17/18 stores outstanding ->
// forces the 2 DMAs retired (19->17 or 20->17), stores keep flowing.

typedef float f32x4 __attribute__((ext_vector_type(4)));

constexpr unsigned B  = 1024;
constexpr unsigned A  = 64;
constexpr unsigned D  = 8;
constexpr unsigned F  = 62;
constexpr unsigned K  = D + 1;                   // 9 output rows per atom
constexpr unsigned F2 = F / 2;                   // 31 float2 per feature row
constexpr unsigned ROWTAB = A * K;               // 576 source-row entries
constexpr unsigned ATOMS4_PER_B = A * F / 4;     // 992 float4 staged per batch
constexpr unsigned OUT4_PER_B   = A * K * F / 4; // 8928 float4 per batch
constexpr unsigned NT = 512;                     // threads per block

__device__ __forceinline__ void gload_lds16(const f32x4* g, f32x4* l) {
    __builtin_amdgcn_global_load_lds(
        (const __attribute__((address_space(1))) void*)g,
        (__attribute__((address_space(3))) void*)l,
        16, 0, 0);
}

__device__ __forceinline__ void stage_atoms(f32x4* s, const f32x4* src,
                                            unsigned tid) {
    gload_lds16(src + tid, s + tid);                       // i = 0..511
    if (tid < ATOMS4_PER_B - NT)                           // i = 512..991
        gload_lds16(src + tid + NT, s + tid + NT);
}

__device__ __forceinline__ void fill_rowtab(int* s_row, int e, unsigned tid) {
    if (tid < A) s_row[tid * K] = (int)tid;                // k==0: self
    s_row[(tid >> 3) * K + (tid & 7) + 1] = e;             // k=1..8: edges
}

__device__ __forceinline__ void store_batch(f32x4* __restrict__ dst,
                                            const float2* __restrict__ s_at,
                                            const int* __restrict__ s_row,
                                            unsigned tid) {
    for (unsigned t = tid; t < OUT4_PER_B; t += NT) {
        float2 h0, h1;
        {
            const unsigned o = 2 * t;          // float2 index (rows are 31 f2)
            const unsigned r = o / F2;
            const unsigned e = o - r * F2;
            const int idx = s_row[r];
            h0 = (idx >= 0) ? s_at[(unsigned)idx * F2 + e]
                            : make_float2(0.0f, 0.0f);
        }
        {
            const unsigned o = 2 * t + 1;
            const unsigned r = o / F2;
            const unsigned e = o - r * F2;
            const int idx = s_row[r];
            h1 = (idx >= 0) ? s_at[(unsigned)idx * F2 + e]
                            : make_float2(0.0f, 0.0f);
        }
        f32x4 v = { h0.x, h0.y, h1.x, h1.y };
        dst[t] = v;
    }
}

__global__ __launch_bounds__(NT)
void graph_lookup_kernel(const f32x4* __restrict__ atoms4,
                         const int*   __restrict__ edges,
                         f32x4*       __restrict__ out4)
{
    __shared__ alignas(16) float2 sA[A * F2];   // 15.5 KB each
    __shared__ alignas(16) float2 sB[A * F2];
    __shared__ int rA[ROWTAB];                  // 2.25 KB each
    __shared__ int rB[ROWTAB];

    const unsigned tid = threadIdx.x;
    const unsigned b0  = blockIdx.x * 2;
    const unsigned b1  = b0 + 1;

    // Phase 1: b0's stage DMA + BOTH edge loads.
    stage_atoms((f32x4*)sA, atoms4 + (size_t)b0 * ATOMS4_PER_B, tid);
    const int e0 = edges[(size_t)b0 * (A * D) + tid];      // A*D == NT
    const int e1 = edges[(size_t)b1 * (A * D) + tid];

    // Keep b1's DMAs strictly AFTER phase-1 VMEM in issue order, so
    // vmcnt(2) below leaves exactly them outstanding.
    __builtin_amdgcn_sched_barrier(0);

    // Phase 2: issue b1's stage DMA immediately — overlaps b0's stage
    // latency and the whole b0 store loop.
    stage_atoms((f32x4*)sB, atoms4 + (size_t)b1 * ATOMS4_PER_B, tid);

    fill_rowtab(rA, e0, tid);
    // Own b0 DMA + e0/e1 retired (<=2 outstanding == b1's DMAs); rowtab
    // ds_writes drained. Stores haven't started, so no store drain here.
    asm volatile("s_waitcnt vmcnt(2) lgkmcnt(0)" ::: "memory");
    __builtin_amdgcn_s_barrier();

    store_batch(out4 + (size_t)b0 * OUT4_PER_B, sA, rA, tid);

    fill_rowtab(rB, e1, tid);   // e1 long since in a register
    // Per-wave outstanding: 2 b1-DMAs + 17/18 stores. vmcnt(17) forces the
    // DMAs retired while leaving up to 17 stores in flight across the
    // barrier -> the HBM write stream never drains.
    asm volatile("s_waitcnt vmcnt(17) lgkmcnt(0)" ::: "memory");
    __builtin_amdgcn_s_barrier();

    store_batch(out4 + (size_t)b1 * OUT4_PER_B, sB, rB, tid);
}

extern "C" void kernel_launch(void* const* d_in, const int* in_sizes, int n_in,
                              void* d_out, int out_size, void* d_ws, size_t ws_size,
                              hipStream_t stream) {
    const f32x4* atoms4 = (const f32x4*)d_in[0];
    const int*   edges  = (const int*)d_in[1];
    f32x4*       out4   = (f32x4*)d_out;

    graph_lookup_kernel<<<B / 2, NT, 0, stream>>>(atoms4, edges, out4);
}

// Round 3
// 29.535 us; speedup vs baseline: 1.1277x; 1.0117x over previous
//
#include <hip/hip_runtime.h>

// GraphLookup: atoms [B,A,F] f32, edges [B,A,D] int32 (neighbor idx, -1 = none)
// out [B,A,D+1,F]: out[:,:,0,:] = atoms; out[:,:,1+d,:] = atoms[b, edges[b,a,d], :]
//
// Round-3 structure: FULL-OCCUPANCY single-batch blocks.
// Rounds 1-2 falsified barrier-drain and read/write-interleave theories
// (counted-vmcnt pipelining == plain __syncthreads == 29.4-29.9 us).
// The double-buffered 2-batch design cost half the chip's wave slots
// (35.5 KB LDS -> 2 blocks/CU = 16 waves) for pipeline overlap that
// measurably buys nothing. This version: 1024 blocks x 512 threads,
// one batch per block, 17.75 KB LDS -> 4 blocks/CU = 32 waves/CU (full),
// ONE barrier (nothing but own DMAs before it -> drain is free), 2x the
// per-CU in-flight store queue.

typedef float f32x4 __attribute__((ext_vector_type(4)));

constexpr unsigned B  = 1024;
constexpr unsigned A  = 64;
constexpr unsigned D  = 8;
constexpr unsigned F  = 62;
constexpr unsigned K  = D + 1;                   // 9 output rows per atom
constexpr unsigned F2 = F / 2;                   // 31 float2 per feature row
constexpr unsigned ROWTAB = A * K;               // 576 source-row entries
constexpr unsigned ATOMS4_PER_B = A * F / 4;     // 992 float4 staged per batch
constexpr unsigned OUT4_PER_B   = A * K * F / 4; // 8928 float4 per batch
constexpr unsigned NT = 512;                     // threads per block

// Async global->LDS, 16B per lane; per-thread dst = base + tid*16 matches
// the HW wave-uniform-base + lane*16 rule for linear layout.
__device__ __forceinline__ void gload_lds16(const f32x4* g, f32x4* l) {
    __builtin_amdgcn_global_load_lds(
        (const __attribute__((address_space(1))) void*)g,
        (__attribute__((address_space(3))) void*)l,
        16, 0, 0);
}

__global__ __launch_bounds__(NT, 8)              // 8 waves/EU -> 4 blocks/CU
void graph_lookup_kernel(const f32x4* __restrict__ atoms4,
                         const int*   __restrict__ edges,
                         f32x4*       __restrict__ out4)
{
    __shared__ alignas(16) float2 sA[A * F2];    // 15.5 KB
    __shared__ int s_row[ROWTAB];                // 2.25 KB

    const unsigned tid = threadIdx.x;
    const unsigned b   = blockIdx.x;

    // Stage this batch's atoms slab (2 DMA loads/thread) + row table.
    {
        const f32x4* src = atoms4 + (size_t)b * ATOMS4_PER_B;
        f32x4* s = (f32x4*)sA;
        gload_lds16(src + tid, s + tid);                   // i = 0..511
        if (tid < ATOMS4_PER_B - NT)                       // i = 512..991
            gload_lds16(src + tid + NT, s + tid + NT);

        const int e = edges[(size_t)b * (A * D) + tid];    // A*D == NT
        if (tid < A) s_row[tid * K] = (int)tid;            // k==0: self
        s_row[(tid >> 3) * K + (tid & 7) + 1] = e;         // k=1..8: edges
    }
    // Only the block's own DMAs + edge load are outstanding here; no
    // stores have been issued, so the implicit vmcnt(0) drain is free.
    __syncthreads();

    f32x4* __restrict__ dst = out4 + (size_t)b * OUT4_PER_B;

    // Flat f32x4 store stream; each f32x4 = two float2 gathers that may
    // straddle a row boundary (rows are 31 float2). Second division CSE'd
    // into a carry off the first.
    for (unsigned t = tid; t < OUT4_PER_B; t += NT) {
        const unsigned o  = 2 * t;                 // float2 index
        const unsigned r0 = o / F2;                // magic-mul div by 31
        const unsigned e0 = o - r0 * F2;
        const bool cross  = (e0 == F2 - 1);        // second half rolls over
        const unsigned r1 = r0 + (cross ? 1u : 0u);
        const unsigned e1 = cross ? 0u : e0 + 1u;

        const int i0 = s_row[r0];
        const int i1 = s_row[r1];

        const float2 h0 = (i0 >= 0) ? sA[(unsigned)i0 * F2 + e0]
                                    : make_float2(0.0f, 0.0f);
        const float2 h1 = (i1 >= 0) ? sA[(unsigned)i1 * F2 + e1]
                                    : make_float2(0.0f, 0.0f);

        f32x4 v = { h0.x, h0.y, h1.x, h1.y };
        dst[t] = v;
    }
}

extern "C" void kernel_launch(void* const* d_in, const int* in_sizes, int n_in,
                              void* d_out, int out_size, void* d_ws, size_t ws_size,
                              hipStream_t stream) {
    const f32x4* atoms4 = (const f32x4*)d_in[0];
    const int*   edges  = (const int*)d_in[1];
    f32x4*       out4   = (f32x4*)d_out;

    graph_lookup_kernel<<<B, NT, 0, stream>>>(atoms4, edges, out4);
}